// Round 20
// baseline (201.278 us; speedup 1.0000x reference)
//
#include <hip/hip_runtime.h>
#include <hip/hip_bf16.h>

#define NN 100000
#define NE 1600000
#define DIM 64
#define NG 64

#define NBUK 391      // coarse buckets of 256 nodes: bucket = col >> 8
#define EPB 4096      // edges per pass-1 block
#define NBLK 391      // ceil(NE/EPB)

typedef float fvec2 __attribute__((ext_vector_type(2)));

static __device__ __forceinline__ unsigned short bf16bits(float v) {
    __hip_bfloat16 b = __float2bfloat16(v);
    return *reinterpret_cast<unsigned short*>(&b);
}
// fp8 e4m3 (OCP) HW converts: 4 fp8 <-> 4 f32 per dword
static __device__ __forceinline__ void fp8x4(unsigned w, float& a, float& b, float& c, float& d) {
    fvec2 lo = __builtin_amdgcn_cvt_pk_f32_fp8((int)w, false);
    fvec2 hi = __builtin_amdgcn_cvt_pk_f32_fp8((int)w, true);
    a = lo[0]; b = lo[1]; c = hi[0]; d = hi[1];
}
static __device__ __forceinline__ unsigned fp8pack4(float a, float b, float c, float d) {
    int w = __builtin_amdgcn_cvt_pk_fp8_f32(a, b, 0, false);
    w = __builtin_amdgcn_cvt_pk_fp8_f32(c, d, w, true);
    return (unsigned)w;
}
// csr pack: row(17 bits) | signless-bf16 ew(15 bits). ew >= 0 always.
static __device__ __forceinline__ unsigned csr_pack(int r, float w) {
    unsigned u = __float_as_uint(w);
    unsigned nb = ((u + 0x8000u) >> 16) & 0x7FFFu;
    return ((unsigned)r << 15) | nb;
}
static __device__ __forceinline__ float csr_w(unsigned u) {
    return __uint_as_float((u & 0x7FFFu) << 16);
}

// ---------------- per-block bucket histogram (persisted) + global counts ----------
__global__ __launch_bounds__(1024) void k_ghist2(const int* __restrict__ col,
                                                 int* __restrict__ hist2d,
                                                 int* gcnt, int E) {
    __shared__ int hist[NBUK];
    int t = threadIdx.x;
    for (int i = t; i < NBUK; i += 1024) hist[i] = 0;
    __syncthreads();
    int e0 = blockIdx.x * EPB, e1 = min(e0 + EPB, E);
    for (int e = e0 + t; e < e1; e += 1024) atomicAdd(&hist[col[e] >> 8], 1);
    __syncthreads();
    for (int i = t; i < NBUK; i += 1024) {
        int c = hist[i];
        hist2d[blockIdx.x * NBUK + i] = c;
        if (c) atomicAdd(&gcnt[i], c);
    }
}

// ---------------- bucket offsets scan (one block) + zero pool buffers ----------
__global__ __launch_bounds__(256) void k_gscan(const int* __restrict__ gcnt,
                                               int* __restrict__ boff,
                                               float* __restrict__ sums,
                                               float* __restrict__ cntf) {
    __shared__ int sm[256];
    int t = threadIdx.x;
    for (int i = t; i < NG * DIM; i += 256) sums[i] = 0.f;
    if (t < NG) cntf[t] = 0.f;
    int v0 = (2 * t < NBUK) ? gcnt[2 * t] : 0;
    int v1 = (2 * t + 1 < NBUK) ? gcnt[2 * t + 1] : 0;
    int s = v0 + v1;
    sm[t] = s;
    __syncthreads();
    for (int off = 1; off < 256; off <<= 1) {
        int tmp = (t >= off) ? sm[t - off] : 0;
        __syncthreads();
        sm[t] += tmp;
        __syncthreads();
    }
    int run = sm[t] - s;
    if (2 * t < NBUK) boff[2 * t] = run;
    run += v0;
    if (2 * t + 1 < NBUK) boff[2 * t + 1] = run;
    if (t == 255) boff[NBUK] = run + v1;  // == NE
}

// ---------------- per-(block,bucket) base scan ----------------
__global__ __launch_bounds__(256) void k_colscan(const int* __restrict__ hist2d,
                                                 const int* __restrict__ boff,
                                                 int* __restrict__ base2d) {
    __shared__ int sm[256];
    int b = blockIdx.x, t = threadIdx.x;
    int v0 = (2 * t < NBLK) ? hist2d[(size_t)(2 * t) * NBUK + b] : 0;
    int v1 = (2 * t + 1 < NBLK) ? hist2d[(size_t)(2 * t + 1) * NBUK + b] : 0;
    int s = v0 + v1;
    sm[t] = s;
    __syncthreads();
    for (int off = 1; off < 256; off <<= 1) {
        int tmp = (t >= off) ? sm[t - off] : 0;
        __syncthreads();
        sm[t] += tmp;
        __syncthreads();
    }
    int run = boff[b] + sm[t] - s;
    if (2 * t < NBLK) base2d[(size_t)(2 * t) * NBUK + b] = run;
    run += v0;
    if (2 * t + 1 < NBLK) base2d[(size_t)(2 * t + 1) * NBUK + b] = run;
}

// ---------------- pass 1 v2: single pass, precomputed bases, no global atomics ----
// binned record: .x = (cl<<17)|row  (cl = col&255, row<2^17), .y = ew bits
__global__ __launch_bounds__(1024) void k_part1v2(const int* __restrict__ row,
                                                  const int* __restrict__ col,
                                                  const float* __restrict__ ew,
                                                  const int* __restrict__ base2d,
                                                  int2* __restrict__ binned, int E) {
    __shared__ int cur[NBUK];
    int t = threadIdx.x;
    for (int i = t; i < NBUK; i += 1024) cur[i] = base2d[(size_t)blockIdx.x * NBUK + i];
    __syncthreads();
    int e0 = blockIdx.x * EPB, e1 = min(e0 + EPB, E);
    for (int e = e0 + t; e < e1; e += 1024) {
        int c = col[e];
        int b = c >> 8, cl = c & 255;
        int p = atomicAdd(&cur[b], 1);
        binned[p] = make_int2((cl << 17) | row[e], __float_as_int(ew[e]));
    }
}

// ---------------- fused pass 2: degree+rowptr+dinv, csr place, x->h' cast (fp8) ----
__global__ __launch_bounds__(256) void k_p2(const int2* __restrict__ binned,
                                            const int* __restrict__ boff,
                                            float* __restrict__ dinv,
                                            int* __restrict__ rowptr,
                                            unsigned* __restrict__ csr,
                                            const float* __restrict__ x,
                                            unsigned* __restrict__ xb) {
    int b = blockIdx.x, t = threadIdx.x;
    __shared__ unsigned int dsum[256];
    __shared__ int ncnt[256];
    __shared__ int sm[256];
    __shared__ float ldin[256];
    __shared__ int ncur[256];
    dsum[t] = 0;
    ncnt[t] = 0;
    __syncthreads();
    int e0 = boff[b], e1 = boff[b + 1];
    for (int e = e0 + t; e < e1; e += 256) {
        int2 v = binned[e];
        int cl = v.x >> 17;
        atomicAdd(&ncnt[cl], 1);
        unsigned int fx = (unsigned int)__float2uint_rn(__int_as_float(v.y) * 16777216.0f);
        atomicAdd(&dsum[cl], fx);
    }
    __syncthreads();
    int c = ncnt[t];
    sm[t] = c;
    __syncthreads();
    for (int off = 1; off < 256; off <<= 1) {
        int tmp = (t >= off) ? sm[t - off] : 0;
        __syncthreads();
        sm[t] += tmp;
        __syncthreads();
    }
    int node = b * 256 + t;
    float dv = rsqrtf(1.0f + (float)dsum[t] * (1.0f / 16777216.0f));
    int rp = e0 + sm[t] - c;
    ldin[t] = dv;
    ncur[t] = rp;
    if (node < NN) {
        rowptr[node] = rp;
        dinv[node] = dv;
    }
    if (b == 0 && t == 0) rowptr[NN] = NE;
    __syncthreads();
    // csr place (binned window L2-warm)
    for (int e = e0 + t; e < e1; e += 256) {
        int2 v = binned[e];
        int cl = v.x >> 17, r = v.x & 0x1FFFF;
        int p = atomicAdd(&ncur[cl], 1);
        csr[p] = csr_pack(r, __int_as_float(v.y));
    }
    // cast this bucket's x rows to h' = x*dinv (fp8), 16 dwords/node
    int nfirst = b * 256;
    int nlast = min(nfirst + 256, NN);
    for (int idx = t; idx < (nlast - nfirst) * 16; idx += 256) {
        int nl = idx >> 4, q = idx & 15;
        float dvn = ldin[nl];
        float4 v = ((const float4*)x)[(size_t)(nfirst + nl) * 16 + q];
        xb[(size_t)(nfirst + nl) * 16 + q] =
            fp8pack4(v.x * dvn, v.y * dvn, v.z * dvn, v.w * dvn);
    }
}

// ---------------- fused gather + GEMM (fp8 h'): out = fp8(relu(g@W+b)*dinv) -------
__global__ __launch_bounds__(256, 7) void k_gg(const int* __restrict__ rowptr,
                                               const unsigned* __restrict__ csr,
                                               const uint2* __restrict__ hf8,
                                               const float* __restrict__ dinv,
                                               const float* __restrict__ W,
                                               const float* __restrict__ b,
                                               unsigned* __restrict__ out) {
    __shared__ float sW[64][64];   // [k][d]
    __shared__ float sX[16][68];   // [node][k], +4 pad
    int tid = threadIdx.x;
#pragma unroll
    for (int i = 0; i < 4; ++i) {
        int q = tid + i * 256;
        ((float4*)&sW[0][0])[q] = ((const float4*)W)[q];
    }
    // ---- gather phase ----
    int node = blockIdx.x * 16 + (tid >> 4);
    int l = tid & 15;
    int g2 = l >> 3, sub = l & 7;
    float dv = dinv[node];
    float acc[8];
#pragma unroll
    for (int i = 0; i < 8; ++i) acc[i] = 0.f;
    if (g2 == 0) {  // self-loop term
        uint2 v = hf8[(size_t)node * 8 + sub];
        fp8x4(v.x, acc[0], acc[1], acc[2], acc[3]);
        fp8x4(v.y, acc[4], acc[5], acc[6], acc[7]);
    }
    int e1 = rowptr[node + 1];
    int e = rowptr[node] + g2;
    unsigned p[4];
#pragma unroll
    for (int i = 0; i < 4; ++i) {
        p[i] = 0u;
        if (e + 2 * i < e1) p[i] = csr[e + 2 * i];
    }
    while (e < e1) {
        uint2 r[4];
#pragma unroll
        for (int i = 0; i < 4; ++i) {
            r[i] = make_uint2(0u, 0u);
            if (e + 2 * i < e1) r[i] = hf8[(size_t)(p[i] >> 15) * 8 + sub];
        }
        int en = e + 8;
        unsigned q[4];
#pragma unroll
        for (int i = 0; i < 4; ++i) {
            q[i] = 0u;
            if (en + 2 * i < e1) q[i] = csr[en + 2 * i];
        }
#pragma unroll
        for (int i = 0; i < 4; ++i) {
            float nm = csr_w(p[i]);
            float f0, f1, f2, f3, f4, f5, f6, f7;
            fp8x4(r[i].x, f0, f1, f2, f3);
            fp8x4(r[i].y, f4, f5, f6, f7);
            acc[0] = fmaf(f0, nm, acc[0]); acc[1] = fmaf(f1, nm, acc[1]);
            acc[2] = fmaf(f2, nm, acc[2]); acc[3] = fmaf(f3, nm, acc[3]);
            acc[4] = fmaf(f4, nm, acc[4]); acc[5] = fmaf(f5, nm, acc[5]);
            acc[6] = fmaf(f6, nm, acc[6]); acc[7] = fmaf(f7, nm, acc[7]);
        }
#pragma unroll
        for (int i = 0; i < 4; ++i) p[i] = q[i];
        e = en;
    }
#pragma unroll
    for (int i = 0; i < 8; ++i) acc[i] += __shfl_xor(acc[i], 8);
    if (g2 == 0) {
        int c = tid >> 4;
        *(float4*)&sX[c][sub * 8 + 0] = make_float4(acc[0] * dv, acc[1] * dv, acc[2] * dv, acc[3] * dv);
        *(float4*)&sX[c][sub * 8 + 4] = make_float4(acc[4] * dv, acc[5] * dv, acc[6] * dv, acc[7] * dv);
    }
    __syncthreads();
    // ---- GEMM phase ----
    int nl = tid >> 4, dg = tid & 15;
    float a0 = 0.f, a1 = 0.f, a2 = 0.f, a3 = 0.f;
#pragma unroll 4
    for (int k4 = 0; k4 < 16; ++k4) {
        float4 xr = *(const float4*)&sX[nl][k4 * 4];
        float4 w0 = *(const float4*)&sW[k4 * 4 + 0][dg * 4];
        float4 w1 = *(const float4*)&sW[k4 * 4 + 1][dg * 4];
        float4 w2 = *(const float4*)&sW[k4 * 4 + 2][dg * 4];
        float4 w3 = *(const float4*)&sW[k4 * 4 + 3][dg * 4];
        a0 = fmaf(xr.x, w0.x, a0); a1 = fmaf(xr.x, w0.y, a1);
        a2 = fmaf(xr.x, w0.z, a2); a3 = fmaf(xr.x, w0.w, a3);
        a0 = fmaf(xr.y, w1.x, a0); a1 = fmaf(xr.y, w1.y, a1);
        a2 = fmaf(xr.y, w1.z, a2); a3 = fmaf(xr.y, w1.w, a3);
        a0 = fmaf(xr.z, w2.x, a0); a1 = fmaf(xr.z, w2.y, a1);
        a2 = fmaf(xr.z, w2.z, a2); a3 = fmaf(xr.z, w2.w, a3);
        a0 = fmaf(xr.w, w3.x, a0); a1 = fmaf(xr.w, w3.y, a1);
        a2 = fmaf(xr.w, w3.z, a2); a3 = fmaf(xr.w, w3.w, a3);
    }
    float4 bv = ((const float4*)b)[dg];
    out[(size_t)(blockIdx.x * 16 + nl) * 16 + dg] =
        fp8pack4(fmaxf(a0 + bv.x, 0.f) * dv, fmaxf(a1 + bv.y, 0.f) * dv,
                 fmaxf(a2 + bv.z, 0.f) * dv, fmaxf(a3 + bv.w, 0.f) * dv);
}

// ---------------- fused final gather + mean-pool accumulate ----------------
// 64 nodes/block, 1024 threads (16 lanes/node, gather7 structure). Gathered row
// (dinv-scaled) accumulates into LDS gsum[group][dim]; one flush per block.
#define GPN 64
__global__ __launch_bounds__(1024) void k_gp(const int* __restrict__ rowptr,
                                             const unsigned* __restrict__ csr,
                                             const uint2* __restrict__ hf8,
                                             const float* __restrict__ dinv,
                                             const int* __restrict__ batch,
                                             float* sums, float* cntf, int n) {
    __shared__ float gsum[64][65];  // [group-g0][dim], +1 pad
    __shared__ float gcl[64];
    int t = threadIdx.x;
    for (int i = t; i < 64 * 65; i += 1024) (&gsum[0][0])[i] = 0.f;
    if (t < 64) gcl[t] = 0.f;
    __syncthreads();
    int base = blockIdx.x * GPN;
    int node = base + (t >> 4);
    int l = t & 15;
    int g2 = l >> 3, sub = l & 7;
    int g0 = batch[base];
    if (node < n) {
        float dv = dinv[node];
        float acc[8];
#pragma unroll
        for (int i = 0; i < 8; ++i) acc[i] = 0.f;
        if (g2 == 0) {  // self-loop term
            uint2 v = hf8[(size_t)node * 8 + sub];
            fp8x4(v.x, acc[0], acc[1], acc[2], acc[3]);
            fp8x4(v.y, acc[4], acc[5], acc[6], acc[7]);
        }
        int e1 = rowptr[node + 1];
        int e = rowptr[node] + g2;
        unsigned p[4];
#pragma unroll
        for (int i = 0; i < 4; ++i) {
            p[i] = 0u;
            if (e + 2 * i < e1) p[i] = csr[e + 2 * i];
        }
        while (e < e1) {
            uint2 r[4];
#pragma unroll
            for (int i = 0; i < 4; ++i) {
                r[i] = make_uint2(0u, 0u);
                if (e + 2 * i < e1) r[i] = hf8[(size_t)(p[i] >> 15) * 8 + sub];
            }
            int en = e + 8;
            unsigned q[4];
#pragma unroll
            for (int i = 0; i < 4; ++i) {
                q[i] = 0u;
                if (en + 2 * i < e1) q[i] = csr[en + 2 * i];
            }
#pragma unroll
            for (int i = 0; i < 4; ++i) {
                float nm = csr_w(p[i]);
                float f0, f1, f2, f3, f4, f5, f6, f7;
                fp8x4(r[i].x, f0, f1, f2, f3);
                fp8x4(r[i].y, f4, f5, f6, f7);
                acc[0] = fmaf(f0, nm, acc[0]); acc[1] = fmaf(f1, nm, acc[1]);
                acc[2] = fmaf(f2, nm, acc[2]); acc[3] = fmaf(f3, nm, acc[3]);
                acc[4] = fmaf(f4, nm, acc[4]); acc[5] = fmaf(f5, nm, acc[5]);
                acc[6] = fmaf(f6, nm, acc[6]); acc[7] = fmaf(f7, nm, acc[7]);
            }
#pragma unroll
            for (int i = 0; i < 4; ++i) p[i] = q[i];
            e = en;
        }
#pragma unroll
        for (int i = 0; i < 8; ++i) acc[i] += __shfl_xor(acc[i], 8);
        if (g2 == 0) {
            int gl = batch[node] - g0;
            float* dst = &gsum[gl][sub * 8];
#pragma unroll
            for (int i = 0; i < 8; ++i) atomicAdd(dst + i, acc[i] * dv);
            if (l == 0) atomicAdd(&gcl[gl], 1.0f);
        }
    }
    __syncthreads();
    int end = min(base + GPN, n);
    int g1 = batch[end - 1];
    int ngr = g1 - g0 + 1;
    for (int idx = t; idx < ngr * 64; idx += 1024) {
        int gl = idx >> 6, d = idx & 63;
        float v = gsum[gl][d];
        if (v != 0.f) atomicAdd(&sums[(g0 + gl) * DIM + d], v);
    }
    if (t < ngr) {
        float c = gcl[t];
        if (c != 0.f) atomicAdd(&cntf[g0 + t], c);
    }
}

// ---------------- head: mean -> @W2+b2 -> fc1 relu -> fc2 -> out ----------------
__global__ __launch_bounds__(64) void k_head(const float* __restrict__ sums,
                                             const float* __restrict__ cnt,
                                             const float* __restrict__ W2,
                                             const float* __restrict__ b2,
                                             const float* __restrict__ fc1w,
                                             const float* __restrict__ fc1b,
                                             const float* __restrict__ fc2w,
                                             const float* __restrict__ fc2b,
                                             const float* __restrict__ ow,
                                             const float* __restrict__ ob,
                                             float* __restrict__ out) {
    int g = blockIdx.x;
    int t = threadIdx.x;
    __shared__ float gv[64];
    __shared__ float tv[64];
    float c = fmaxf(cnt[g], 1.0f);
    gv[t] = sums[g * DIM + t] / c;
    __syncthreads();
    float acc2 = b2[t];
#pragma unroll
    for (int k = 0; k < 64; ++k) acc2 = fmaf(gv[k], W2[k * 64 + t], acc2);
    tv[t] = acc2;
    __syncthreads();
    float r = 0.0f;
    if (t < 32) {
        float acc = fc1b[t];
#pragma unroll
        for (int k = 0; k < 64; ++k) acc = fmaf(tv[k], fc1w[k * 32 + t], acc);
        acc = fmaxf(acc, 0.0f);
        r = acc * fc2w[t];
    }
#pragma unroll
    for (int off = 16; off; off >>= 1) r += __shfl_down(r, off);
    if (t == 0) out[g] = (r + fc2b[0]) * ow[0] + ob[0];
}

extern "C" void kernel_launch(void* const* d_in, const int* in_sizes, int n_in,
                              void* d_out, int out_size, void* d_ws, size_t ws_size,
                              hipStream_t stream) {
    const float* x   = (const float*)d_in[0];
    const int* eidx  = (const int*)d_in[1];
    const float* ew  = (const float*)d_in[2];
    const int* batch = (const int*)d_in[3];
    const float* W0  = (const float*)d_in[4];
    const float* b0  = (const float*)d_in[5];
    const float* W1  = (const float*)d_in[6];
    const float* b1  = (const float*)d_in[7];
    const float* W2  = (const float*)d_in[8];
    const float* b2  = (const float*)d_in[9];
    const float* fc1w = (const float*)d_in[10];
    const float* fc1b = (const float*)d_in[11];
    const float* fc2w = (const float*)d_in[12];
    const float* fc2b = (const float*)d_in[13];
    const float* ow   = (const float*)d_in[14];
    const float* ob   = (const float*)d_in[15];
    float* out = (float*)d_out;

    const int* row = eidx;
    const int* col = eidx + NE;

    // workspace layout (16B-aligned blocks first)
    char* ws = (char*)d_ws;
    int2* binned           = (int2*)ws;               ws += sizeof(int2) * NE;                 // 12.8MB
    unsigned* csr          = (unsigned*)ws;           ws += sizeof(unsigned) * NE;             // 6.4MB
    unsigned* Xf8          = (unsigned*)ws;           ws += sizeof(unsigned) * (size_t)NN * 16; // 6.4MB fp8
    unsigned* Hf8          = (unsigned*)ws;           ws += sizeof(unsigned) * (size_t)NN * 16; // 6.4MB fp8
    int*   hist2d          = (int*)ws;                ws += sizeof(int) * (size_t)NBLK * NBUK; // 611KB
    int*   base2d          = (int*)ws;                ws += sizeof(int) * (size_t)NBLK * NBUK; // 611KB
    float* dinv            = (float*)ws;              ws += sizeof(float) * NN;
    int*   rowptr          = (int*)ws;                ws += sizeof(int) * (NN + 1);
    int*   gcnt            = (int*)ws;                ws += sizeof(int) * (NBUK + 1);
    int*   boff            = (int*)ws;                ws += sizeof(int) * (NBUK + 1);
    float* sums            = (float*)ws;              ws += sizeof(float) * NG * DIM;
    float* cntf            = (float*)ws;              ws += sizeof(float) * NG;

    // ---- CSR build: persisted per-block hists + deterministic bases ----
    hipMemsetAsync(gcnt, 0, sizeof(int) * NBUK, stream);
    k_ghist2<<<NBLK, 1024, 0, stream>>>(col, hist2d, gcnt, NE);
    k_gscan<<<1, 256, 0, stream>>>(gcnt, boff, sums, cntf);
    k_colscan<<<NBUK, 256, 0, stream>>>(hist2d, boff, base2d);
    k_part1v2<<<NBLK, 1024, 0, stream>>>(row, col, ew, base2d, binned, NE);
    k_p2<<<NBUK, 256, 0, stream>>>(binned, boff, dinv, rowptr, csr, x, Xf8);

    int gg_blocks = NN / 16;  // 6250, exact (NN % 16 == 0)
    int gp_blocks = (NN + GPN - 1) / GPN;  // 1563

    // fused layers 0,1: fp8 h' pipeline
    k_gg<<<gg_blocks, 256, 0, stream>>>(rowptr, csr, (const uint2*)Xf8, dinv, W0, b0, Hf8);
    k_gg<<<gg_blocks, 256, 0, stream>>>(rowptr, csr, (const uint2*)Hf8, dinv, W1, b1, Xf8);

    // layer 2: fused gather + mean-pool accumulate; W2/b2 folded into head
    k_gp<<<gp_blocks, 1024, 0, stream>>>(rowptr, csr, (const uint2*)Xf8, dinv, batch, sums, cntf, NN);
    k_head<<<NG, 64, 0, stream>>>(sums, cntf, W2, b2, fc1w, fc1b, fc2w, fc2b, ow, ob, out);
}

// Round 21
// 182.983 us; speedup vs baseline: 1.1000x; 1.1000x over previous
//
#include <hip/hip_runtime.h>
#include <hip/hip_bf16.h>

#define NN 100000
#define NE 1600000
#define DIM 64
#define NG 64

#define NBUK 391      // coarse buckets of 256 nodes: bucket = col >> 8
#define EPB 4096      // edges per pass-1 block
#define NBLK 391      // ceil(NE/EPB)

typedef float fvec2 __attribute__((ext_vector_type(2)));

static __device__ __forceinline__ unsigned short bf16bits(float v) {
    __hip_bfloat16 b = __float2bfloat16(v);
    return *reinterpret_cast<unsigned short*>(&b);
}
// fp8 e4m3 (OCP) HW converts: 4 fp8 <-> 4 f32 per dword
static __device__ __forceinline__ void fp8x4(unsigned w, float& a, float& b, float& c, float& d) {
    fvec2 lo = __builtin_amdgcn_cvt_pk_f32_fp8((int)w, false);
    fvec2 hi = __builtin_amdgcn_cvt_pk_f32_fp8((int)w, true);
    a = lo[0]; b = lo[1]; c = hi[0]; d = hi[1];
}
static __device__ __forceinline__ unsigned fp8pack4(float a, float b, float c, float d) {
    int w = __builtin_amdgcn_cvt_pk_fp8_f32(a, b, 0, false);
    w = __builtin_amdgcn_cvt_pk_fp8_f32(c, d, w, true);
    return (unsigned)w;
}
// csr pack: row(17 bits) | signless-bf16 ew(15 bits). ew >= 0 always.
static __device__ __forceinline__ unsigned csr_pack(int r, float w) {
    unsigned u = __float_as_uint(w);
    unsigned nb = ((u + 0x8000u) >> 16) & 0x7FFFu;
    return ((unsigned)r << 15) | nb;
}
static __device__ __forceinline__ float csr_w(unsigned u) {
    return __uint_as_float((u & 0x7FFFu) << 16);
}

// ---------------- per-block bucket histogram (persisted) + global counts ----------
__global__ __launch_bounds__(1024) void k_ghist2(const int* __restrict__ col,
                                                 int* __restrict__ hist2d,
                                                 int* gcnt, int E) {
    __shared__ int hist[NBUK];
    int t = threadIdx.x;
    for (int i = t; i < NBUK; i += 1024) hist[i] = 0;
    __syncthreads();
    int e0 = blockIdx.x * EPB, e1 = min(e0 + EPB, E);
    for (int e = e0 + t; e < e1; e += 1024) atomicAdd(&hist[col[e] >> 8], 1);
    __syncthreads();
    for (int i = t; i < NBUK; i += 1024) {
        int c = hist[i];
        hist2d[blockIdx.x * NBUK + i] = c;
        if (c) atomicAdd(&gcnt[i], c);
    }
}

// ---------------- bucket offsets scan (one block) + zero pool buffers ----------
__global__ __launch_bounds__(256) void k_gscan(const int* __restrict__ gcnt,
                                               int* __restrict__ boff,
                                               float* __restrict__ sums,
                                               float* __restrict__ cntf) {
    __shared__ int sm[256];
    int t = threadIdx.x;
    for (int i = t; i < NG * DIM; i += 256) sums[i] = 0.f;
    if (t < NG) cntf[t] = 0.f;
    int v0 = (2 * t < NBUK) ? gcnt[2 * t] : 0;
    int v1 = (2 * t + 1 < NBUK) ? gcnt[2 * t + 1] : 0;
    int s = v0 + v1;
    sm[t] = s;
    __syncthreads();
    for (int off = 1; off < 256; off <<= 1) {
        int tmp = (t >= off) ? sm[t - off] : 0;
        __syncthreads();
        sm[t] += tmp;
        __syncthreads();
    }
    int run = sm[t] - s;
    if (2 * t < NBUK) boff[2 * t] = run;
    run += v0;
    if (2 * t + 1 < NBUK) boff[2 * t + 1] = run;
    if (t == 255) boff[NBUK] = run + v1;  // == NE
}

// ---------------- per-(block,bucket) base scan ----------------
__global__ __launch_bounds__(256) void k_colscan(const int* __restrict__ hist2d,
                                                 const int* __restrict__ boff,
                                                 int* __restrict__ base2d) {
    __shared__ int sm[256];
    int b = blockIdx.x, t = threadIdx.x;
    int v0 = (2 * t < NBLK) ? hist2d[(size_t)(2 * t) * NBUK + b] : 0;
    int v1 = (2 * t + 1 < NBLK) ? hist2d[(size_t)(2 * t + 1) * NBUK + b] : 0;
    int s = v0 + v1;
    sm[t] = s;
    __syncthreads();
    for (int off = 1; off < 256; off <<= 1) {
        int tmp = (t >= off) ? sm[t - off] : 0;
        __syncthreads();
        sm[t] += tmp;
        __syncthreads();
    }
    int run = boff[b] + sm[t] - s;
    if (2 * t < NBLK) base2d[(size_t)(2 * t) * NBUK + b] = run;
    run += v0;
    if (2 * t + 1 < NBLK) base2d[(size_t)(2 * t + 1) * NBUK + b] = run;
}

// ---------------- pass 1 v2: single pass, precomputed bases, no global atomics ----
// binned record: .x = (cl<<17)|row  (cl = col&255, row<2^17), .y = ew bits
__global__ __launch_bounds__(1024) void k_part1v2(const int* __restrict__ row,
                                                  const int* __restrict__ col,
                                                  const float* __restrict__ ew,
                                                  const int* __restrict__ base2d,
                                                  int2* __restrict__ binned, int E) {
    __shared__ int cur[NBUK];
    int t = threadIdx.x;
    for (int i = t; i < NBUK; i += 1024) cur[i] = base2d[(size_t)blockIdx.x * NBUK + i];
    __syncthreads();
    int e0 = blockIdx.x * EPB, e1 = min(e0 + EPB, E);
    for (int e = e0 + t; e < e1; e += 1024) {
        int c = col[e];
        int b = c >> 8, cl = c & 255;
        int p = atomicAdd(&cur[b], 1);
        binned[p] = make_int2((cl << 17) | row[e], __float_as_int(ew[e]));
    }
}

// ---------------- fused pass 2: degree+rowptr+dinv, csr place, x->h' cast (fp8) ----
__global__ __launch_bounds__(256) void k_p2(const int2* __restrict__ binned,
                                            const int* __restrict__ boff,
                                            float* __restrict__ dinv,
                                            int* __restrict__ rowptr,
                                            unsigned* __restrict__ csr,
                                            const float* __restrict__ x,
                                            unsigned* __restrict__ xb) {
    int b = blockIdx.x, t = threadIdx.x;
    __shared__ unsigned int dsum[256];
    __shared__ int ncnt[256];
    __shared__ int sm[256];
    __shared__ float ldin[256];
    __shared__ int ncur[256];
    dsum[t] = 0;
    ncnt[t] = 0;
    __syncthreads();
    int e0 = boff[b], e1 = boff[b + 1];
    for (int e = e0 + t; e < e1; e += 256) {
        int2 v = binned[e];
        int cl = v.x >> 17;
        atomicAdd(&ncnt[cl], 1);
        unsigned int fx = (unsigned int)__float2uint_rn(__int_as_float(v.y) * 16777216.0f);
        atomicAdd(&dsum[cl], fx);
    }
    __syncthreads();
    int c = ncnt[t];
    sm[t] = c;
    __syncthreads();
    for (int off = 1; off < 256; off <<= 1) {
        int tmp = (t >= off) ? sm[t - off] : 0;
        __syncthreads();
        sm[t] += tmp;
        __syncthreads();
    }
    int node = b * 256 + t;
    float dv = rsqrtf(1.0f + (float)dsum[t] * (1.0f / 16777216.0f));
    int rp = e0 + sm[t] - c;
    ldin[t] = dv;
    ncur[t] = rp;
    if (node < NN) {
        rowptr[node] = rp;
        dinv[node] = dv;
    }
    if (b == 0 && t == 0) rowptr[NN] = NE;
    __syncthreads();
    // csr place (binned window L2-warm)
    for (int e = e0 + t; e < e1; e += 256) {
        int2 v = binned[e];
        int cl = v.x >> 17, r = v.x & 0x1FFFF;
        int p = atomicAdd(&ncur[cl], 1);
        csr[p] = csr_pack(r, __int_as_float(v.y));
    }
    // cast this bucket's x rows to h' = x*dinv (fp8), 16 dwords/node
    int nfirst = b * 256;
    int nlast = min(nfirst + 256, NN);
    for (int idx = t; idx < (nlast - nfirst) * 16; idx += 256) {
        int nl = idx >> 4, q = idx & 15;
        float dvn = ldin[nl];
        float4 v = ((const float4*)x)[(size_t)(nfirst + nl) * 16 + q];
        xb[(size_t)(nfirst + nl) * 16 + q] =
            fp8pack4(v.x * dvn, v.y * dvn, v.z * dvn, v.w * dvn);
    }
}

// ---------------- fused gather + GEMM (fp8 h'): out = fp8(relu(g@W+b)*dinv) -------
__global__ __launch_bounds__(256, 7) void k_gg(const int* __restrict__ rowptr,
                                               const unsigned* __restrict__ csr,
                                               const uint2* __restrict__ hf8,
                                               const float* __restrict__ dinv,
                                               const float* __restrict__ W,
                                               const float* __restrict__ b,
                                               unsigned* __restrict__ out) {
    __shared__ float sW[64][64];   // [k][d]
    __shared__ float sX[16][68];   // [node][k], +4 pad
    int tid = threadIdx.x;
#pragma unroll
    for (int i = 0; i < 4; ++i) {
        int q = tid + i * 256;
        ((float4*)&sW[0][0])[q] = ((const float4*)W)[q];
    }
    // ---- gather phase ----
    int node = blockIdx.x * 16 + (tid >> 4);
    int l = tid & 15;
    int g2 = l >> 3, sub = l & 7;
    float dv = dinv[node];
    float acc[8];
#pragma unroll
    for (int i = 0; i < 8; ++i) acc[i] = 0.f;
    if (g2 == 0) {  // self-loop term
        uint2 v = hf8[(size_t)node * 8 + sub];
        fp8x4(v.x, acc[0], acc[1], acc[2], acc[3]);
        fp8x4(v.y, acc[4], acc[5], acc[6], acc[7]);
    }
    int e1 = rowptr[node + 1];
    int e = rowptr[node] + g2;
    unsigned p[4];
#pragma unroll
    for (int i = 0; i < 4; ++i) {
        p[i] = 0u;
        if (e + 2 * i < e1) p[i] = csr[e + 2 * i];
    }
    while (e < e1) {
        uint2 r[4];
#pragma unroll
        for (int i = 0; i < 4; ++i) {
            r[i] = make_uint2(0u, 0u);
            if (e + 2 * i < e1) r[i] = hf8[(size_t)(p[i] >> 15) * 8 + sub];
        }
        int en = e + 8;
        unsigned q[4];
#pragma unroll
        for (int i = 0; i < 4; ++i) {
            q[i] = 0u;
            if (en + 2 * i < e1) q[i] = csr[en + 2 * i];
        }
#pragma unroll
        for (int i = 0; i < 4; ++i) {
            float nm = csr_w(p[i]);
            float f0, f1, f2, f3, f4, f5, f6, f7;
            fp8x4(r[i].x, f0, f1, f2, f3);
            fp8x4(r[i].y, f4, f5, f6, f7);
            acc[0] = fmaf(f0, nm, acc[0]); acc[1] = fmaf(f1, nm, acc[1]);
            acc[2] = fmaf(f2, nm, acc[2]); acc[3] = fmaf(f3, nm, acc[3]);
            acc[4] = fmaf(f4, nm, acc[4]); acc[5] = fmaf(f5, nm, acc[5]);
            acc[6] = fmaf(f6, nm, acc[6]); acc[7] = fmaf(f7, nm, acc[7]);
        }
#pragma unroll
        for (int i = 0; i < 4; ++i) p[i] = q[i];
        e = en;
    }
#pragma unroll
    for (int i = 0; i < 8; ++i) acc[i] += __shfl_xor(acc[i], 8);
    if (g2 == 0) {
        int c = tid >> 4;
        *(float4*)&sX[c][sub * 8 + 0] = make_float4(acc[0] * dv, acc[1] * dv, acc[2] * dv, acc[3] * dv);
        *(float4*)&sX[c][sub * 8 + 4] = make_float4(acc[4] * dv, acc[5] * dv, acc[6] * dv, acc[7] * dv);
    }
    __syncthreads();
    // ---- GEMM phase ----
    int nl = tid >> 4, dg = tid & 15;
    float a0 = 0.f, a1 = 0.f, a2 = 0.f, a3 = 0.f;
#pragma unroll 4
    for (int k4 = 0; k4 < 16; ++k4) {
        float4 xr = *(const float4*)&sX[nl][k4 * 4];
        float4 w0 = *(const float4*)&sW[k4 * 4 + 0][dg * 4];
        float4 w1 = *(const float4*)&sW[k4 * 4 + 1][dg * 4];
        float4 w2 = *(const float4*)&sW[k4 * 4 + 2][dg * 4];
        float4 w3 = *(const float4*)&sW[k4 * 4 + 3][dg * 4];
        a0 = fmaf(xr.x, w0.x, a0); a1 = fmaf(xr.x, w0.y, a1);
        a2 = fmaf(xr.x, w0.z, a2); a3 = fmaf(xr.x, w0.w, a3);
        a0 = fmaf(xr.y, w1.x, a0); a1 = fmaf(xr.y, w1.y, a1);
        a2 = fmaf(xr.y, w1.z, a2); a3 = fmaf(xr.y, w1.w, a3);
        a0 = fmaf(xr.z, w2.x, a0); a1 = fmaf(xr.z, w2.y, a1);
        a2 = fmaf(xr.z, w2.z, a2); a3 = fmaf(xr.z, w2.w, a3);
        a0 = fmaf(xr.w, w3.x, a0); a1 = fmaf(xr.w, w3.y, a1);
        a2 = fmaf(xr.w, w3.z, a2); a3 = fmaf(xr.w, w3.w, a3);
    }
    float4 bv = ((const float4*)b)[dg];
    out[(size_t)(blockIdx.x * 16 + nl) * 16 + dg] =
        fp8pack4(fmaxf(a0 + bv.x, 0.f) * dv, fmaxf(a1 + bv.y, 0.f) * dv,
                 fmaxf(a2 + bv.z, 0.f) * dv, fmaxf(a3 + bv.w, 0.f) * dv);
}

// ---------------- gather v7 (last layer): fp8 in, true-value bf16 out -------------
__global__ __launch_bounds__(256) void k_gather7(const int* __restrict__ rowptr,
                                                 const unsigned* __restrict__ csr,
                                                 const uint2* __restrict__ hf8,
                                                 const float* __restrict__ dinv,
                                                 uint4* __restrict__ out, int n) {
    int tid = threadIdx.x;
    int node = blockIdx.x * 16 + (tid >> 4);
    if (node >= n) return;
    int l = tid & 15;
    int g2 = l >> 3, sub = l & 7;
    float dv = dinv[node];
    float acc[8];
#pragma unroll
    for (int i = 0; i < 8; ++i) acc[i] = 0.f;
    if (g2 == 0) {  // self-loop term
        uint2 v = hf8[(size_t)node * 8 + sub];
        fp8x4(v.x, acc[0], acc[1], acc[2], acc[3]);
        fp8x4(v.y, acc[4], acc[5], acc[6], acc[7]);
    }
    int e1 = rowptr[node + 1];
    int e = rowptr[node] + g2;
    unsigned p[4];
#pragma unroll
    for (int i = 0; i < 4; ++i) {
        p[i] = 0u;
        if (e + 2 * i < e1) p[i] = csr[e + 2 * i];
    }
    while (e < e1) {
        uint2 r[4];
#pragma unroll
        for (int i = 0; i < 4; ++i) {
            r[i] = make_uint2(0u, 0u);
            if (e + 2 * i < e1) r[i] = hf8[(size_t)(p[i] >> 15) * 8 + sub];
        }
        int en = e + 8;
        unsigned q[4];
#pragma unroll
        for (int i = 0; i < 4; ++i) {
            q[i] = 0u;
            if (en + 2 * i < e1) q[i] = csr[en + 2 * i];
        }
#pragma unroll
        for (int i = 0; i < 4; ++i) {
            float nm = csr_w(p[i]);
            float f0, f1, f2, f3, f4, f5, f6, f7;
            fp8x4(r[i].x, f0, f1, f2, f3);
            fp8x4(r[i].y, f4, f5, f6, f7);
            acc[0] = fmaf(f0, nm, acc[0]); acc[1] = fmaf(f1, nm, acc[1]);
            acc[2] = fmaf(f2, nm, acc[2]); acc[3] = fmaf(f3, nm, acc[3]);
            acc[4] = fmaf(f4, nm, acc[4]); acc[5] = fmaf(f5, nm, acc[5]);
            acc[6] = fmaf(f6, nm, acc[6]); acc[7] = fmaf(f7, nm, acc[7]);
        }
#pragma unroll
        for (int i = 0; i < 4; ++i) p[i] = q[i];
        e = en;
    }
#pragma unroll
    for (int i = 0; i < 8; ++i) acc[i] += __shfl_xor(acc[i], 8);
    if (g2 == 0) {
        uint4 o;
        o.x = ((unsigned int)bf16bits(acc[1] * dv) << 16) | bf16bits(acc[0] * dv);
        o.y = ((unsigned int)bf16bits(acc[3] * dv) << 16) | bf16bits(acc[2] * dv);
        o.z = ((unsigned int)bf16bits(acc[5] * dv) << 16) | bf16bits(acc[4] * dv);
        o.w = ((unsigned int)bf16bits(acc[7] * dv) << 16) | bf16bits(acc[6] * dv);
        out[(size_t)node * 8 + sub] = o;
    }
}

// unpack packed bf16x2 dword -> two floats (pool input)
static __device__ __forceinline__ void bf2x(unsigned int u, float& lo, float& hi) {
    lo = __uint_as_float(u << 16);
    hi = __uint_as_float(u & 0xFFFF0000u);
}

// ---------------- pooling v3: LDS-staged two-level reduction ----------------
#define PB3 512
__global__ __launch_bounds__(256) void k_pool3(const int* __restrict__ batch,
                                               const uint4* __restrict__ h8,
                                               float* sums, float* cnt, int n) {
    __shared__ float gsum[64][65];  // [group-g0][dim], +1 pad
    __shared__ float gcl[64];
    int t = threadIdx.x;
    for (int i = t; i < 64 * 65; i += 256) (&gsum[0][0])[i] = 0.f;
    if (t < 64) gcl[t] = 0.f;
    __syncthreads();
    int base = blockIdx.x * PB3;
    int end = min(base + PB3, n);
    int g0 = batch[base];
    int cl = t >> 3, sub = t & 7;
    float acc[8];
#pragma unroll
    for (int i = 0; i < 8; ++i) acc[i] = 0.f;
    int gcur = -1, runlen = 0;
    for (int node = base + cl; node < end; node += 32) {
        int g = batch[node];
        if (g != gcur) {
            if (gcur >= 0) {
                int gl = gcur - g0;
#pragma unroll
                for (int i = 0; i < 8; ++i) atomicAdd(&gsum[gl][sub * 8 + i], acc[i]);
                if (sub == 0) atomicAdd(&gcl[gl], (float)runlen);
#pragma unroll
                for (int i = 0; i < 8; ++i) acc[i] = 0.f;
            }
            gcur = g;
            runlen = 0;
        }
        uint4 v = h8[(size_t)node * 8 + sub];
        float lo, hi;
        bf2x(v.x, lo, hi); acc[0] += lo; acc[1] += hi;
        bf2x(v.y, lo, hi); acc[2] += lo; acc[3] += hi;
        bf2x(v.z, lo, hi); acc[4] += lo; acc[5] += hi;
        bf2x(v.w, lo, hi); acc[6] += lo; acc[7] += hi;
        runlen++;
    }
    if (gcur >= 0) {
        int gl = gcur - g0;
#pragma unroll
        for (int i = 0; i < 8; ++i) atomicAdd(&gsum[gl][sub * 8 + i], acc[i]);
        if (sub == 0) atomicAdd(&gcl[gl], (float)runlen);
    }
    __syncthreads();
    int g1 = batch[end - 1];
    int ngr = g1 - g0 + 1;
    for (int idx = t; idx < ngr * 64; idx += 256) {
        int gl = idx >> 6, d = idx & 63;
        float v = gsum[gl][d];
        if (v != 0.f) atomicAdd(&sums[(g0 + gl) * DIM + d], v);
    }
    if (t < ngr) {
        float c = gcl[t];
        if (c != 0.f) atomicAdd(&cnt[g0 + t], c);
    }
}

// ---------------- head: mean -> @W2+b2 -> fc1 relu -> fc2 -> out ----------------
__global__ __launch_bounds__(64) void k_head(const float* __restrict__ sums,
                                             const float* __restrict__ cnt,
                                             const float* __restrict__ W2,
                                             const float* __restrict__ b2,
                                             const float* __restrict__ fc1w,
                                             const float* __restrict__ fc1b,
                                             const float* __restrict__ fc2w,
                                             const float* __restrict__ fc2b,
                                             const float* __restrict__ ow,
                                             const float* __restrict__ ob,
                                             float* __restrict__ out) {
    int g = blockIdx.x;
    int t = threadIdx.x;
    __shared__ float gv[64];
    __shared__ float tv[64];
    float c = fmaxf(cnt[g], 1.0f);
    gv[t] = sums[g * DIM + t] / c;
    __syncthreads();
    float acc2 = b2[t];
#pragma unroll
    for (int k = 0; k < 64; ++k) acc2 = fmaf(gv[k], W2[k * 64 + t], acc2);
    tv[t] = acc2;
    __syncthreads();
    float r = 0.0f;
    if (t < 32) {
        float acc = fc1b[t];
#pragma unroll
        for (int k = 0; k < 64; ++k) acc = fmaf(tv[k], fc1w[k * 32 + t], acc);
        acc = fmaxf(acc, 0.0f);
        r = acc * fc2w[t];
    }
#pragma unroll
    for (int off = 16; off; off >>= 1) r += __shfl_down(r, off);
    if (t == 0) out[g] = (r + fc2b[0]) * ow[0] + ob[0];
}

extern "C" void kernel_launch(void* const* d_in, const int* in_sizes, int n_in,
                              void* d_out, int out_size, void* d_ws, size_t ws_size,
                              hipStream_t stream) {
    const float* x   = (const float*)d_in[0];
    const int* eidx  = (const int*)d_in[1];
    const float* ew  = (const float*)d_in[2];
    const int* batch = (const int*)d_in[3];
    const float* W0  = (const float*)d_in[4];
    const float* b0  = (const float*)d_in[5];
    const float* W1  = (const float*)d_in[6];
    const float* b1  = (const float*)d_in[7];
    const float* W2  = (const float*)d_in[8];
    const float* b2  = (const float*)d_in[9];
    const float* fc1w = (const float*)d_in[10];
    const float* fc1b = (const float*)d_in[11];
    const float* fc2w = (const float*)d_in[12];
    const float* fc2b = (const float*)d_in[13];
    const float* ow   = (const float*)d_in[14];
    const float* ob   = (const float*)d_in[15];
    float* out = (float*)d_out;

    const int* row = eidx;
    const int* col = eidx + NE;

    // workspace layout (16B-aligned blocks first)
    char* ws = (char*)d_ws;
    int2* binned           = (int2*)ws;               ws += sizeof(int2) * NE;                 // 12.8MB
    unsigned* csr          = (unsigned*)ws;           ws += sizeof(unsigned) * NE;             // 6.4MB
    unsigned* Xf8          = (unsigned*)ws;           ws += sizeof(unsigned) * (size_t)NN * 16; // 6.4MB fp8
    unsigned* Hf8          = (unsigned*)ws;           ws += sizeof(unsigned) * (size_t)NN * 16; // 6.4MB fp8
    __hip_bfloat16* Hb16   = (__hip_bfloat16*)ws;     ws += sizeof(__hip_bfloat16) * (size_t)NN * DIM; // 12.8MB
    int*   hist2d          = (int*)ws;                ws += sizeof(int) * (size_t)NBLK * NBUK; // 611KB
    int*   base2d          = (int*)ws;                ws += sizeof(int) * (size_t)NBLK * NBUK; // 611KB
    float* dinv            = (float*)ws;              ws += sizeof(float) * NN;
    int*   rowptr          = (int*)ws;                ws += sizeof(int) * (NN + 1);
    int*   gcnt            = (int*)ws;                ws += sizeof(int) * (NBUK + 1);
    int*   boff            = (int*)ws;                ws += sizeof(int) * (NBUK + 1);
    float* sums            = (float*)ws;              ws += sizeof(float) * NG * DIM;
    float* cntf            = (float*)ws;              ws += sizeof(float) * NG;

    // ---- CSR build: persisted per-block hists + deterministic bases ----
    hipMemsetAsync(gcnt, 0, sizeof(int) * NBUK, stream);
    k_ghist2<<<NBLK, 1024, 0, stream>>>(col, hist2d, gcnt, NE);
    k_gscan<<<1, 256, 0, stream>>>(gcnt, boff, sums, cntf);
    k_colscan<<<NBUK, 256, 0, stream>>>(hist2d, boff, base2d);
    k_part1v2<<<NBLK, 1024, 0, stream>>>(row, col, ew, base2d, binned, NE);
    k_p2<<<NBUK, 256, 0, stream>>>(binned, boff, dinv, rowptr, csr, x, Xf8);

    int gg_blocks = NN / 16;  // 6250, exact (NN % 16 == 0)

    // fused layers 0,1: fp8 h' pipeline
    k_gg<<<gg_blocks, 256, 0, stream>>>(rowptr, csr, (const uint2*)Xf8, dinv, W0, b0, Hf8);
    k_gg<<<gg_blocks, 256, 0, stream>>>(rowptr, csr, (const uint2*)Hf8, dinv, W1, b1, Xf8);

    // layer 2 gather (fp8 in, true-value bf16 out) -> pool; W2/b2 folded into head
    k_gather7<<<gg_blocks, 256, 0, stream>>>(rowptr, csr, (const uint2*)Xf8, dinv, (uint4*)Hb16, NN);
    k_pool3<<<(NN + PB3 - 1) / PB3, 256, 0, stream>>>(batch, (const uint4*)Hb16, sums, cntf, NN);
    k_head<<<NG, 64, 0, stream>>>(sums, cntf, W2, b2, fc1w, fc1b, fc2w, fc2b, ow, ob, out);
}